// Round 5
// baseline (491.703 us; speedup 1.0000x reference)
//
#include <hip/hip_runtime.h>

// Problem constants
constexpr int Bb = 8, Ll = 2048, Ww = 1024;
constexpr int BL = Bb * Ll;              // 16384

typedef short bf16x8 __attribute__((ext_vector_type(8)));
typedef float f32x4  __attribute__((ext_vector_type(4)));

// ---------- bf16 helpers (RNE) ----------
__device__ inline unsigned short f2bf(float f) {
    union { float f; unsigned u; } v; v.f = f;
    unsigned u = v.u;
    unsigned r = (u + 0x7fffu + ((u >> 16) & 1u)) >> 16;
    return (unsigned short)r;
}
__device__ inline float bf2f(unsigned short h) {
    union { unsigned u; float f; } v; v.u = ((unsigned)h) << 16;
    return v.f;
}

// ---------- async global->LDS, 16B per lane ----------
__device__ inline void gl_lds16(const unsigned short* g, unsigned short* l) {
    __builtin_amdgcn_global_load_lds(
        (const __attribute__((address_space(1))) unsigned int*)g,
        (__attribute__((address_space(3))) unsigned int*)l, 16, 0, 0);
}

// ---------- kernel 0: mask dtype detect + expand to float (1=valid, 0=padded) ----------
__global__ void mask_expand_kernel(const void* __restrict__ mraw, float* __restrict__ maskf) {
    const unsigned char* mb = (const unsigned char*)mraw;
    const unsigned* mw = (const unsigned*)mraw;
    __shared__ int s_nonint, s_notf, s_hasf;
    if (threadIdx.x == 0) { s_nonint = 0; s_notf = 0; s_hasf = 0; }
    __syncthreads();
    int nonint = 0, notf = 0, hasf = 0;
    for (int i = threadIdx.x; i < BL; i += blockDim.x) {
        unsigned char c = mb[i];
        if ((i & 3) && c) nonint = 1;
    }
    for (int i = threadIdx.x; i < BL / 4; i += blockDim.x) {
        unsigned w = mw[i];
        if (w == 0x3f800000u) hasf = 1; else if (w) notf = 1;
    }
    if (nonint) atomicOr(&s_nonint, 1);
    if (notf)   atomicOr(&s_notf, 1);
    if (hasf)   atomicOr(&s_hasf, 1);
    __syncthreads();
    int is_f32  = (!s_notf) && s_hasf;
    int is_bool = (!is_f32) && s_nonint;
    for (int i = threadIdx.x; i < BL; i += blockDim.x) {
        int masked;
        if (is_bool) masked = (mb[i] != 0);
        else         masked = (mw[i] != 0u);
        maskf[i] = masked ? 0.0f : 1.0f;
    }
}

// ---------- kernel 1a: conv_w fp32 [g][o][c][k] -> pre-tiled swizzled bf16 images ----------
__global__ void wconv_kernel(const float* __restrict__ conv_w, unsigned short* __restrict__ w_t) {
    int gnt = blockIdx.x >> 2;           // 0..39 = g*20+nt
    int part = blockIdx.x & 3;
    int g = gnt / 20, nt = gnt % 20;
    int k = nt >> 2, o0 = (nt & 3) * 128;
    int tid = threadIdx.x;
    #pragma unroll
    for (int it = 0; it < 8; it++) {
        int chunk = part * 2048 + it * 256 + tid;    // 0..8191 per (g,nt)
        int r = chunk >> 6;                           // tile row
        int cq = chunk & 63;
        int cs = cq >> 2, q = cq & 3;
        int o = o0 + r;
        int c0 = cs * 32 + q * 8;                     // channel within group
        const float* src = conv_w + (((size_t)(g * 512 + o) * 512 + c0) * 5 + k);
        ushort4 lo, hi;
        lo.x = f2bf(src[0]);  lo.y = f2bf(src[5]);  lo.z = f2bf(src[10]); lo.w = f2bf(src[15]);
        hi.x = f2bf(src[20]); hi.y = f2bf(src[25]); hi.z = f2bf(src[30]); hi.w = f2bf(src[35]);
        int dst16 = (gnt * 16 + cs) * 512 + r * 4 + (q ^ (r & 3));
        *(ushort4*)&w_t[(size_t)dst16 * 8]     = lo;
        *(ushort4*)&w_t[(size_t)dst16 * 8 + 4] = hi;
    }
}

// ---------- kernel 1b: offsets + x->tiled bf16. One wave per row, no barriers. ----------
__global__ __launch_bounds__(256) void offsets_kernel(
    const float* __restrict__ x, const float* __restrict__ w_off, const float* __restrict__ b_off,
    unsigned short* __restrict__ x_t, int* __restrict__ idx0, int* __restrict__ idx1,
    float* __restrict__ w0a, float* __restrict__ w1a)
{
    const int wave = threadIdx.x >> 6, lane = threadIdx.x & 63;
    const int bl = blockIdx.x * 4 + wave;
    const int b = bl >> 11;
    const int l = bl & (Ll - 1);
    const int lt = l >> 7, r = l & 127;
    const int c0 = lane * 16;

    const float* xr = x + (size_t)bl * Ww + c0;
    float4 v0 = *(const float4*)(xr + 0);
    float4 v1 = *(const float4*)(xr + 4);
    float4 v2 = *(const float4*)(xr + 8);
    float4 v3 = *(const float4*)(xr + 12);
    float xv[16] = { v0.x,v0.y,v0.z,v0.w, v1.x,v1.y,v1.z,v1.w,
                     v2.x,v2.y,v2.z,v2.w, v3.x,v3.y,v3.z,v3.w };

    uint4 pa, pb;
    unsigned* pu = (unsigned*)&pa;
    #pragma unroll
    for (int j = 0; j < 4; j++) pu[j] = (unsigned)f2bf(xv[j*2]) | ((unsigned)f2bf(xv[j*2+1]) << 16);
    pu = (unsigned*)&pb;
    #pragma unroll
    for (int j = 0; j < 4; j++) pu[j] = (unsigned)f2bf(xv[8+j*2]) | ((unsigned)f2bf(xv[8+j*2+1]) << 16);
    const int cs = lane >> 1, q0 = (lane & 1) * 2;
    const size_t ib = ((size_t)(b * 16 + lt) * 32 + cs) * 512 + r * 4;
    *(uint4*)&x_t[(ib + (q0 ^ (r & 3))) * 8]       = pa;
    *(uint4*)&x_t[(ib + ((q0 + 1) ^ (r & 3))) * 8] = pb;

    float acc[5] = {0.f, 0.f, 0.f, 0.f, 0.f};
    const float* wp = w_off + (size_t)c0 * 5;
    #pragma unroll
    for (int j = 0; j < 16; j++) {
        #pragma unroll
        for (int k = 0; k < 5; k++) acc[k] += xv[j] * wp[j * 5 + k];
    }
    #pragma unroll
    for (int k = 0; k < 5; k++)
        #pragma unroll
        for (int off = 32; off; off >>= 1) acc[k] += __shfl_xor(acc[k], off);

    if (lane < 5) {
        float s = (lane == 0) ? acc[0] : (lane == 1) ? acc[1] : (lane == 2) ? acc[2]
                : (lane == 3) ? acc[3] : acc[4];
        s += b_off[lane];
        float offv = tanhf(s) * 2.0f;
        float pos = (float)l + (float)(lane - 2) + offv;
        float p0 = floorf(pos);
        float frac = pos - p0;
        int i0 = (int)p0;
        int i1 = i0 + 1;
        int ok0 = (i0 >= 0) && (i0 < Ll);
        int ok1 = (i1 >= 0) && (i1 < Ll);
        idx0[bl * 5 + lane] = min(max(i0, 0), Ll - 1);
        idx1[bl * 5 + lane] = min(max(i1, 0), Ll - 1);
        w0a[bl * 5 + lane] = ok0 ? (1.0f - frac) : 0.0f;
        w1a[bl * 5 + lane] = ok1 ? frac : 0.0f;
    }
}

// ---------- kernel 2: A-resident GEMM. grid (g,b,mt) = 256 blocks = 1/CU. ----------
__global__ __launch_bounds__(256) void gemm_kernel(
    const unsigned short* __restrict__ x_t, const unsigned short* __restrict__ w_t,
    unsigned short* __restrict__ Z)
{
    __shared__ unsigned short As[16 * 4096];   // 128 KB: 16 k-chunk images
    __shared__ unsigned short Bs[2][2 * 4096]; // 2 x 16 KB ping-pong
    const int tid = threadIdx.x;
    const int g  = blockIdx.x;
    const int b  = blockIdx.y;
    const int mt = blockIdx.z;
    const int lane = tid & 63, wave = tid >> 6;
    const int wr = (wave >> 1) * 64, wc = (wave & 1) * 64;
    const int l15 = lane & 15, l4 = lane >> 4;
    const int sw = (l4 ^ (l15 & 3)) * 8;

    const unsigned short* Ab = x_t + ((size_t)((b * 16 + mt) * 32 + g * 16)) * 4096 + tid * 8;
    #pragma unroll
    for (int c = 0; c < 16; c++) {
        gl_lds16(Ab + c * 4096,        &As[c * 4096 + tid * 8]);
        gl_lds16(Ab + c * 4096 + 2048, &As[c * 4096 + tid * 8 + 2048]);
    }
    const unsigned short* Wb = w_t + ((size_t)(g * 20) * 16) * 4096 + tid * 8;
    gl_lds16(Wb,        &Bs[0][tid * 8]);
    gl_lds16(Wb + 2048, &Bs[0][tid * 8 + 2048]);
    gl_lds16(Wb + 4096, &Bs[0][4096 + tid * 8]);
    gl_lds16(Wb + 6144, &Bs[0][4096 + tid * 8 + 2048]);
    __syncthreads();

    f32x4 acc[4][4];
    int buf = 0;
    for (int it = 0; it < 160; ++it) {         // it = nt*8 + ks
        const int nt = it >> 3, ks = it & 7;
        if (it + 1 < 160) {
            const int nt2 = (it + 1) >> 3, ks2 = (it + 1) & 7;
            const unsigned short* gb = w_t + ((size_t)((g * 20 + nt2) * 16 + 2 * ks2)) * 4096 + tid * 8;
            gl_lds16(gb,        &Bs[buf ^ 1][tid * 8]);
            gl_lds16(gb + 2048, &Bs[buf ^ 1][tid * 8 + 2048]);
            gl_lds16(gb + 4096, &Bs[buf ^ 1][4096 + tid * 8]);
            gl_lds16(gb + 6144, &Bs[buf ^ 1][4096 + tid * 8 + 2048]);
        }
        if (ks == 0) {
            #pragma unroll
            for (int i = 0; i < 4; i++)
                #pragma unroll
                for (int j = 0; j < 4; j++) acc[i][j] = (f32x4){0.f, 0.f, 0.f, 0.f};
        }
        bf16x8 af[2][4], bfr[2][4];
        #pragma unroll
        for (int kk = 0; kk < 2; kk++)
            #pragma unroll
            for (int i = 0; i < 4; i++) {
                af[kk][i]  = *(const bf16x8*)&As[(2 * ks + kk) * 4096 + (wr + i * 16 + l15) * 32 + sw];
                bfr[kk][i] = *(const bf16x8*)&Bs[buf][kk * 4096 + (wc + i * 16 + l15) * 32 + sw];
            }
        #pragma unroll
        for (int kk = 0; kk < 2; kk++)
            #pragma unroll
            for (int i = 0; i < 4; i++)
                #pragma unroll
                for (int j = 0; j < 4; j++)
                    acc[i][j] = __builtin_amdgcn_mfma_f32_16x16x32_bf16(af[kk][i], bfr[kk][j], acc[i][j], 0, 0, 0);
        if (ks == 7) {
            const int k = nt >> 2, o0 = (nt & 3) * 128;
            const int gc0 = g * 512 + o0;
            #pragma unroll
            for (int j = 0; j < 4; j++) {
                int col = gc0 + wc + j * 16 + l15;
                #pragma unroll
                for (int i = 0; i < 4; i++) {
                    int row0 = (b * 16 + mt) * 128 + wr + i * 16 + l4 * 4;
                    #pragma unroll
                    for (int rr = 0; rr < 4; rr++)
                        Z[((size_t)(row0 + rr) * 5 + k) * 1024 + col] = f2bf(acc[i][j][rr]);
                }
            }
        }
        __syncthreads();
        buf ^= 1;
    }
}

// ---------- kernel 3: gather/lerp + bias + LayerNorm + mask + pooled partials ----------
// One wave per row; XCD swizzle maps batch b to XCD b (Z window + atomics stay local).
__global__ __launch_bounds__(256) void gather_kernel(
    const unsigned short* __restrict__ Z, const int* __restrict__ idx0, const int* __restrict__ idx1,
    const float* __restrict__ w0a, const float* __restrict__ w1a, const float* __restrict__ conv_b,
    const float* __restrict__ gamma, const float* __restrict__ maskf, float* __restrict__ pooled)
{
    const int v = blockIdx.x + (blockIdx.z << 9);   // grid (512,1,8)
    const int vr = (v & 7) * 512 + (v >> 3);        // XCD-contiguous remap: slice == batch
    const int tid = threadIdx.x;
    const int wave = tid >> 6, lane = tid & 63;
    const int bl = vr * 4 + wave;
    const int b = bl >> 11;
    const int c0 = lane * 16;

    float pacc[16];
    #pragma unroll
    for (int j = 0; j < 16; j++) pacc[j] = 0.f;

    if (maskf[bl] != 0.0f) {
        ushort4 za[5][4], zb[5][4];                 // 4 quads = 16 ch per row-side
        float w0s[5], w1s[5];
        #pragma unroll
        for (int k = 0; k < 5; k++) {
            const int si = bl * 5 + k;
            const int i0 = idx0[si], i1 = idx1[si];
            w0s[k] = w0a[si]; w1s[k] = w1a[si];
            const ushort4* p0 = (const ushort4*)(Z + ((size_t)((b << 11) + i0) * 5 + k) * 1024 + c0);
            const ushort4* p1 = (const ushort4*)(Z + ((size_t)((b << 11) + i1) * 5 + k) * 1024 + c0);
            #pragma unroll
            for (int q = 0; q < 4; q++) { za[k][q] = p0[q]; zb[k][q] = p1[q]; }
        }
        float h[16];
        #pragma unroll
        for (int j = 0; j < 4; j++) {
            float4 cb = *(const float4*)(conv_b + c0 + j * 4);
            h[j*4+0] = cb.x; h[j*4+1] = cb.y; h[j*4+2] = cb.z; h[j*4+3] = cb.w;
        }
        #pragma unroll
        for (int k = 0; k < 5; k++) {
            const float w0 = w0s[k], w1 = w1s[k];
            #pragma unroll
            for (int q = 0; q < 4; q++) {
                h[q*4+0] += w0 * bf2f(za[k][q].x) + w1 * bf2f(zb[k][q].x);
                h[q*4+1] += w0 * bf2f(za[k][q].y) + w1 * bf2f(zb[k][q].y);
                h[q*4+2] += w0 * bf2f(za[k][q].z) + w1 * bf2f(zb[k][q].z);
                h[q*4+3] += w0 * bf2f(za[k][q].w) + w1 * bf2f(zb[k][q].w);
            }
        }
        float s1 = 0.f, s2 = 0.f;
        #pragma unroll
        for (int j = 0; j < 16; j++) { s1 += h[j]; s2 += h[j] * h[j]; }
        #pragma unroll
        for (int off = 32; off; off >>= 1) {
            s1 += __shfl_xor(s1, off);
            s2 += __shfl_xor(s2, off);
        }
        const float mu = s1 * (1.0f / 1024.0f);
        const float var = s2 * (1.0f / 1024.0f) - mu * mu;
        const float rstd = rsqrtf(var + 1e-5f);
        #pragma unroll
        for (int j = 0; j < 4; j++) {
            float4 g4 = *(const float4*)(gamma + c0 + j * 4);
            pacc[j*4+0] = (h[j*4+0] - mu) * rstd * g4.x;
            pacc[j*4+1] = (h[j*4+1] - mu) * rstd * g4.y;
            pacc[j*4+2] = (h[j*4+2] - mu) * rstd * g4.z;
            pacc[j*4+3] = (h[j*4+3] - mu) * rstd * g4.w;
        }
    }
    __shared__ float spool[4][1024];
    #pragma unroll
    for (int j = 0; j < 4; j++)
        *(float4*)&spool[wave][c0 + j * 4] = *(float4*)&pacc[j * 4];
    __syncthreads();
    const int ch = tid * 4;
    float4 a = *(float4*)&spool[0][ch];
    float4 bq = *(float4*)&spool[1][ch];
    float4 cq = *(float4*)&spool[2][ch];
    float4 dq = *(float4*)&spool[3][ch];
    atomicAdd(&pooled[b * Ww + ch + 0], a.x + bq.x + cq.x + dq.x);
    atomicAdd(&pooled[b * Ww + ch + 1], a.y + bq.y + cq.y + dq.y);
    atomicAdd(&pooled[b * Ww + ch + 2], a.z + bq.z + cq.z + dq.z);
    atomicAdd(&pooled[b * Ww + ch + 3], a.w + bq.w + cq.w + dq.w);
}

// ---------- kernel 4: lengths + projection (beta folded: + sum(beta*proj)) ----------
__global__ void final_kernel(const float* __restrict__ pooled, const float* __restrict__ maskf,
                             const float* __restrict__ beta, const float* __restrict__ proj_w,
                             const float* __restrict__ proj_b, float* __restrict__ out)
{
    int b = blockIdx.x;
    int tid = threadIdx.x;
    float len = 0.f, dotP = 0.f, dotB = 0.f;
    for (int l = tid; l < Ll; l += 256) len += maskf[b * Ll + l];
    for (int c = tid; c < Ww; c += 256) {
        dotP += pooled[b * Ww + c] * proj_w[c];
        dotB += beta[c] * proj_w[c];
    }
    for (int off = 32; off; off >>= 1) {
        len += __shfl_down(len, off);
        dotP += __shfl_down(dotP, off);
        dotB += __shfl_down(dotB, off);
    }
    __shared__ float rl[4], rp[4], rb[4];
    int wave = tid >> 6, lane = tid & 63;
    if (lane == 0) { rl[wave] = len; rp[wave] = dotP; rb[wave] = dotB; }
    __syncthreads();
    if (tid == 0) {
        float Lt = rl[0] + rl[1] + rl[2] + rl[3];
        float Pt = rp[0] + rp[1] + rp[2] + rp[3];
        float Bt = rb[0] + rb[1] + rb[2] + rb[3];
        out[b] = Pt / fmaxf(Lt, 1.0f) + Bt + proj_b[0];
    }
}

// ---------- workspace layout (bytes, 16B-aligned) ----------
// maskf @ 0 (65536) · pooled @ 65536 (32768) · idx0 @ 98304 · idx1 @ 425984
// w0a @ 753664 · w1a @ 1081344 · w_t @ 1409024 (5242880) · x_t @ 6651904 (33554432)
// Z @ 40206336 ([16384][5][1024] bf16 = 167772160) -> total 207,978,496 (fits: ran in R4)
constexpr size_t Z_OFF = 40206336;

extern "C" void kernel_launch(void* const* d_in, const int* in_sizes, int n_in,
                              void* d_out, int out_size, void* d_ws, size_t ws_size,
                              hipStream_t stream)
{
    const float* x      = (const float*)d_in[0];
    const void*  mask   = d_in[1];
    const float* w_off  = (const float*)d_in[2];
    const float* b_off  = (const float*)d_in[3];
    const float* conv_w = (const float*)d_in[4];
    const float* conv_b = (const float*)d_in[5];
    const float* gamma  = (const float*)d_in[6];
    const float* beta   = (const float*)d_in[7];
    const float* proj_w = (const float*)d_in[8];
    const float* proj_b = (const float*)d_in[9];
    float* out = (float*)d_out;

    char* ws = (char*)d_ws;
    float* maskf         = (float*)(ws + 0);
    float* pooled        = (float*)(ws + 65536);
    int*   idx0          = (int*)(ws + 98304);
    int*   idx1          = (int*)(ws + 425984);
    float* w0a           = (float*)(ws + 753664);
    float* w1a           = (float*)(ws + 1081344);
    unsigned short* w_t  = (unsigned short*)(ws + 1409024);
    unsigned short* x_t  = (unsigned short*)(ws + 6651904);
    unsigned short* Z    = (unsigned short*)(ws + Z_OFF);

    hipMemsetAsync(pooled, 0, Bb * Ww * sizeof(float), stream);
    mask_expand_kernel<<<1, 256, 0, stream>>>(mask, maskf);
    wconv_kernel<<<160, 256, 0, stream>>>(conv_w, w_t);
    offsets_kernel<<<BL / 4, 256, 0, stream>>>(x, w_off, b_off, x_t, idx0, idx1, w0a, w1a);
    gemm_kernel<<<dim3(2, 8, 16), 256, 0, stream>>>(x_t, w_t, Z);
    gather_kernel<<<dim3(512, 1, 8), 256, 0, stream>>>(Z, idx0, idx1, w0a, w1a, conv_b,
                                                       gamma, maskf, pooled);
    final_kernel<<<8, 256, 0, stream>>>(pooled, maskf, beta, proj_w, proj_b, out);
}

// Round 6
// 353.716 us; speedup vs baseline: 1.3901x; 1.3901x over previous
//
#include <hip/hip_runtime.h>
#include <hip/hip_bf16.h>

// Problem constants
constexpr int Bb = 8, Ll = 2048, Ww = 1024;
constexpr int BL = Bb * Ll;              // 16384

typedef short bf16x8 __attribute__((ext_vector_type(8)));
typedef float f32x4  __attribute__((ext_vector_type(4)));

// ---------- bf16 helpers ----------
__device__ inline unsigned short f2bf(float f) {
    union { float f; unsigned u; } v; v.f = f;
    unsigned u = v.u;
    unsigned r = (u + 0x7fffu + ((u >> 16) & 1u)) >> 16;
    return (unsigned short)r;
}
__device__ inline float bf2f(unsigned short h) {
    union { unsigned u; float f; } v; v.u = ((unsigned)h) << 16;
    return v.f;
}
// lerp two packed bf16 pairs (lo=even ch, hi=odd ch) -> packed bf16 pair
__device__ inline unsigned lerp_pair(unsigned pa, unsigned pb, float w0, float w1) {
    union { unsigned u; float f; } alo, ahi, blo, bhi;
    alo.u = pa << 16;  ahi.u = pa & 0xffff0000u;
    blo.u = pb << 16;  bhi.u = pb & 0xffff0000u;
    float hlo = w0 * alo.f + w1 * blo.f;
    float hhi = w0 * ahi.f + w1 * bhi.f;
    union { __hip_bfloat162 h2; unsigned u; } r;
    r.h2 = __float22bfloat162_rn(float2{hlo, hhi});
    return r.u;
}

// ---------- async global->LDS, 16B per lane ----------
__device__ inline void gl_lds16(const unsigned short* g, unsigned short* l) {
    __builtin_amdgcn_global_load_lds(
        (const __attribute__((address_space(1))) unsigned int*)g,
        (__attribute__((address_space(3))) unsigned int*)l, 16, 0, 0);
}

// ---------- kernel 0a/0b: mask dtype detect (parallel, 2-phase) + expand ----------
__global__ void maskA_kernel(const void* __restrict__ mraw, int* __restrict__ flags) {
    const unsigned char* mb = (const unsigned char*)mraw;
    const unsigned* mw = (const unsigned*)mraw;
    int gid = blockIdx.x * 256 + threadIdx.x;          // 4096 threads
    int nonint = 0, notf = 0, hasf = 0;
    for (int i = gid; i < BL; i += 4096) { if ((i & 3) && mb[i]) nonint = 1; }
    for (int i = gid; i < BL / 4; i += 4096) {
        unsigned w = mw[i];
        if (w == 0x3f800000u) hasf = 1; else if (w) notf = 1;
    }
    if (__builtin_amdgcn_readfirstlane(__ballot(nonint) ? 1 : 0)) { if ((threadIdx.x & 63) == 0 && __ballot(nonint)) atomicOr(&flags[0], 1); }
    if ((threadIdx.x & 63) == 0) {
        // wave-level ballots already folded above for nonint; handle notf/hasf
    }
    if (nonint) atomicOr(&flags[0], 1);
    if (notf)   atomicOr(&flags[1], 1);
    if (hasf)   atomicOr(&flags[2], 1);
}
__global__ void maskB_kernel(const void* __restrict__ mraw, const int* __restrict__ flags,
                             float* __restrict__ maskf) {
    const unsigned char* mb = (const unsigned char*)mraw;
    const unsigned* mw = (const unsigned*)mraw;
    int gid = blockIdx.x * 256 + threadIdx.x;
    int is_f32  = (!flags[1]) && flags[2];
    int is_bool = (!is_f32) && flags[0];
    for (int i = gid; i < BL; i += 4096) {
        int masked = is_bool ? (mb[i] != 0) : (mw[i] != 0u);
        maskf[i] = masked ? 0.0f : 1.0f;
    }
}

// ---------- kernel 1a: conv_w fp32 [g][o][c][k] -> pre-tiled swizzled bf16 images ----------
// Image per (g, nt, cs): 128 rows (cols o) x 32 k-chans; 16B chunk at r*4 + (q^(r&3)).
__global__ void wconv_kernel(const float* __restrict__ conv_w, unsigned short* __restrict__ w_t) {
    int gnt = blockIdx.x >> 2;           // 0..39 = g*20+nt
    int part = blockIdx.x & 3;
    int g = gnt / 20, nt = gnt % 20;
    int k = nt >> 2, o0 = (nt & 3) * 128;
    int tid = threadIdx.x;
    #pragma unroll
    for (int it = 0; it < 8; it++) {
        int chunk = part * 2048 + it * 256 + tid;    // 0..8191 per (g,nt)
        int r = chunk >> 6;
        int cq = chunk & 63;
        int cs = cq >> 2, q = cq & 3;
        int o = o0 + r;
        int c0 = cs * 32 + q * 8;
        const float* src = conv_w + (((size_t)(g * 512 + o) * 512 + c0) * 5 + k);
        ushort4 lo, hi;
        lo.x = f2bf(src[0]);  lo.y = f2bf(src[5]);  lo.z = f2bf(src[10]); lo.w = f2bf(src[15]);
        hi.x = f2bf(src[20]); hi.y = f2bf(src[25]); hi.z = f2bf(src[30]); hi.w = f2bf(src[35]);
        int dst16 = (gnt * 16 + cs) * 512 + r * 4 + (q ^ (r & 3));
        *(ushort4*)&w_t[(size_t)dst16 * 8]     = lo;
        *(ushort4*)&w_t[(size_t)dst16 * 8 + 4] = hi;
    }
}

// ---------- kernel 1b: offsets + x -> plain bf16. One wave per row, no barriers. ----------
// pk[bl][k] = float4{ bitcast(i0), bitcast(i1), w0, w1 }
__global__ __launch_bounds__(256) void offsets_kernel(
    const float* __restrict__ x, const float* __restrict__ w_off, const float* __restrict__ b_off,
    unsigned short* __restrict__ x_bf, float4* __restrict__ pk)
{
    const int wave = threadIdx.x >> 6, lane = threadIdx.x & 63;
    const int bl = blockIdx.x * 4 + wave;
    const int l = bl & (Ll - 1);
    const int c0 = lane * 16;

    const float* xr = x + (size_t)bl * Ww + c0;
    float4 v0 = *(const float4*)(xr + 0);
    float4 v1 = *(const float4*)(xr + 4);
    float4 v2 = *(const float4*)(xr + 8);
    float4 v3 = *(const float4*)(xr + 12);
    float xv[16] = { v0.x,v0.y,v0.z,v0.w, v1.x,v1.y,v1.z,v1.w,
                     v2.x,v2.y,v2.z,v2.w, v3.x,v3.y,v3.z,v3.w };

    uint4 pa, pb;
    unsigned* pu = (unsigned*)&pa;
    #pragma unroll
    for (int j = 0; j < 4; j++) pu[j] = (unsigned)f2bf(xv[j*2]) | ((unsigned)f2bf(xv[j*2+1]) << 16);
    pu = (unsigned*)&pb;
    #pragma unroll
    for (int j = 0; j < 4; j++) pu[j] = (unsigned)f2bf(xv[8+j*2]) | ((unsigned)f2bf(xv[8+j*2+1]) << 16);
    *(uint4*)&x_bf[(size_t)bl * Ww + c0]     = pa;
    *(uint4*)&x_bf[(size_t)bl * Ww + c0 + 8] = pb;

    float acc[5] = {0.f, 0.f, 0.f, 0.f, 0.f};
    const float* wp = w_off + (size_t)c0 * 5;
    #pragma unroll
    for (int j = 0; j < 16; j++) {
        #pragma unroll
        for (int k = 0; k < 5; k++) acc[k] += xv[j] * wp[j * 5 + k];
    }
    #pragma unroll
    for (int k = 0; k < 5; k++)
        #pragma unroll
        for (int off = 32; off; off >>= 1) acc[k] += __shfl_xor(acc[k], off);

    if (lane < 5) {
        float s = (lane == 0) ? acc[0] : (lane == 1) ? acc[1] : (lane == 2) ? acc[2]
                : (lane == 3) ? acc[3] : acc[4];
        s += b_off[lane];
        float offv = tanhf(s) * 2.0f;
        float pos = (float)l + (float)(lane - 2) + offv;
        float p0 = floorf(pos);
        float frac = pos - p0;
        int i0 = (int)p0;
        int i1 = i0 + 1;
        int ok0 = (i0 >= 0) && (i0 < Ll);
        int ok1 = (i1 >= 0) && (i1 < Ll);
        float4 pkv;
        pkv.x = __int_as_float(min(max(i0, 0), Ll - 1));
        pkv.y = __int_as_float(min(max(i1, 0), Ll - 1));
        pkv.z = ok0 ? (1.0f - frac) : 0.0f;
        pkv.w = ok1 ? frac : 0.0f;
        pk[bl * 5 + lane] = pkv;
    }
}

// ---------- kernel 2: fused deform GEMM -> h. Block = 128 rows x 256 cols. ----------
// A fragments built in registers: 16B loads of x_bf rows i0/i1 + packed lerp.
// B streamed via ping-pong global_load_lds of pre-tiled images. Writes h + bias.
__global__ __launch_bounds__(256, 2) void gemm_kernel(
    const unsigned short* __restrict__ x_bf, const unsigned short* __restrict__ w_t,
    const float4* __restrict__ pk, const float* __restrict__ conv_b,
    unsigned short* __restrict__ h)
{
    __shared__ unsigned short Bs[2][2 * 4096];   // 2 x (2 images x 8KB) = 32 KB
    const int tid = threadIdx.x;
    const int mt = blockIdx.x;            // 0..127
    const int nhalf = blockIdx.y;         // 0..1
    const int g = blockIdx.z;             // 0..1
    const int b = mt >> 4;
    const int lane = tid & 63, wave = tid >> 6;
    const int wr = (wave >> 1) * 64;
    const int imgsel = wave & 1;          // column 128-block within the 256
    const int l15 = lane & 15, l4 = lane >> 4;
    const int sw = (l4 ^ (l15 & 3)) * 8;

    // preload B chunk for it=0 (k=0, cs=0): images nt0, nt0+1
    {
        const int nt0 = nhalf * 2;
        const unsigned short* W0 = w_t + ((size_t)((g * 20 + nt0) * 16 + 0)) * 4096;
        const unsigned short* W1 = w_t + ((size_t)((g * 20 + nt0 + 1) * 16 + 0)) * 4096;
        gl_lds16(W0 + tid * 8,        &Bs[0][tid * 8]);
        gl_lds16(W0 + 2048 + tid * 8, &Bs[0][2048 + tid * 8]);
        gl_lds16(W1 + tid * 8,        &Bs[0][4096 + tid * 8]);
        gl_lds16(W1 + 2048 + tid * 8, &Bs[0][4096 + 2048 + tid * 8]);
    }
    __syncthreads();

    f32x4 acc[4][8];
    #pragma unroll
    for (int i = 0; i < 4; i++)
        #pragma unroll
        for (int j = 0; j < 8; j++) acc[i][j] = (f32x4){0.f, 0.f, 0.f, 0.f};

    int buf = 0;
    for (int k = 0; k < 5; ++k) {
        // per-k row metadata (4 rows per lane)
        unsigned off0[4], off1[4];
        float w0r[4], w1r[4];
        #pragma unroll
        for (int i = 0; i < 4; i++) {
            const int bl = mt * 128 + wr + i * 16 + l15;
            float4 pkv = pk[bl * 5 + k];
            const int i0 = __float_as_int(pkv.x), i1 = __float_as_int(pkv.y);
            off0[i] = (unsigned)(((b << 11) + i0) * Ww + g * 512);
            off1[i] = (unsigned)(((b << 11) + i1) * Ww + g * 512);
            w0r[i] = pkv.z; w1r[i] = pkv.w;
        }
        for (int cs = 0; cs < 16; ++cs) {
            const int it = k * 16 + cs;
            if (it < 79) {                       // prefetch next chunk
                const int it2 = it + 1;
                const int k2 = it2 >> 4, cs2 = it2 & 15;
                const int nt0 = k2 * 4 + nhalf * 2;
                const unsigned short* W0 = w_t + ((size_t)((g * 20 + nt0) * 16 + cs2)) * 4096;
                const unsigned short* W1 = w_t + ((size_t)((g * 20 + nt0 + 1) * 16 + cs2)) * 4096;
                gl_lds16(W0 + tid * 8,        &Bs[buf ^ 1][tid * 8]);
                gl_lds16(W0 + 2048 + tid * 8, &Bs[buf ^ 1][2048 + tid * 8]);
                gl_lds16(W1 + tid * 8,        &Bs[buf ^ 1][4096 + tid * 8]);
                gl_lds16(W1 + 2048 + tid * 8, &Bs[buf ^ 1][4096 + 2048 + tid * 8]);
            }
            // build A fragments in registers (deform lerp)
            const int ch0 = cs * 32 + l4 * 8;
            bf16x8 af[4];
            #pragma unroll
            for (int i = 0; i < 4; i++) {
                const uint4 ua = *(const uint4*)(x_bf + off0[i] + ch0);
                const uint4 ub = *(const uint4*)(x_bf + off1[i] + ch0);
                union { unsigned u[4]; bf16x8 v; } fa;
                fa.u[0] = lerp_pair(ua.x, ub.x, w0r[i], w1r[i]);
                fa.u[1] = lerp_pair(ua.y, ub.y, w0r[i], w1r[i]);
                fa.u[2] = lerp_pair(ua.z, ub.z, w0r[i], w1r[i]);
                fa.u[3] = lerp_pair(ua.w, ub.w, w0r[i], w1r[i]);
                af[i] = fa.v;
            }
            // B fragments from LDS image
            bf16x8 bfr[8];
            #pragma unroll
            for (int j = 0; j < 8; j++)
                bfr[j] = *(const bf16x8*)&Bs[buf][imgsel * 4096 + (j * 16 + l15) * 32 + sw];
            #pragma unroll
            for (int i = 0; i < 4; i++)
                #pragma unroll
                for (int j = 0; j < 8; j++)
                    acc[i][j] = __builtin_amdgcn_mfma_f32_16x16x32_bf16(af[i], bfr[j], acc[i][j], 0, 0, 0);
            __syncthreads();
            buf ^= 1;
        }
    }
    // epilogue: + conv_b, store h bf16
    #pragma unroll
    for (int j = 0; j < 8; j++) {
        const int col = g * 512 + nhalf * 256 + imgsel * 128 + j * 16 + l15;
        const float bias = conv_b[col];
        #pragma unroll
        for (int i = 0; i < 4; i++) {
            const int row0 = mt * 128 + wr + i * 16 + l4 * 4;
            #pragma unroll
            for (int rr = 0; rr < 4; rr++)
                h[(size_t)(row0 + rr) * Ww + col] = f2bf(acc[i][j][rr] + bias);
        }
    }
}

// ---------- kernel 3: LayerNorm + mask + pooled partials. One wave per row x4. ----------
__global__ __launch_bounds__(256) void lnpool_kernel(
    const unsigned short* __restrict__ h, const float* __restrict__ gamma,
    const float* __restrict__ maskf, float* __restrict__ pooled)
{
    const int tid = threadIdx.x;
    const int wave = tid >> 6, lane = tid & 63;
    const int c0 = lane * 16;
    const int bl0 = blockIdx.x * 16 + wave * 4;
    const int b = bl0 >> 11;

    float g16[16];
    #pragma unroll
    for (int j = 0; j < 4; j++) {
        float4 gv = *(const float4*)(gamma + c0 + j * 4);
        g16[j*4+0] = gv.x; g16[j*4+1] = gv.y; g16[j*4+2] = gv.z; g16[j*4+3] = gv.w;
    }
    float pacc[16];
    #pragma unroll
    for (int j = 0; j < 16; j++) pacc[j] = 0.f;

    #pragma unroll
    for (int r = 0; r < 4; r++) {
        const int bl = bl0 + r;
        const float m = maskf[bl];
        const uint4 ha = *(const uint4*)(h + (size_t)bl * Ww + c0);
        const uint4 hb = *(const uint4*)(h + (size_t)bl * Ww + c0 + 8);
        float hf[16];
        const unsigned* pw = (const unsigned*)&ha;
        #pragma unroll
        for (int j = 0; j < 4; j++) {
            union { unsigned u; float f; } lo, hi;
            lo.u = pw[j] << 16; hi.u = pw[j] & 0xffff0000u;
            hf[j*2] = lo.f; hf[j*2+1] = hi.f;
        }
        pw = (const unsigned*)&hb;
        #pragma unroll
        for (int j = 0; j < 4; j++) {
            union { unsigned u; float f; } lo, hi;
            lo.u = pw[j] << 16; hi.u = pw[j] & 0xffff0000u;
            hf[8+j*2] = lo.f; hf[8+j*2+1] = hi.f;
        }
        float s1 = 0.f, s2 = 0.f;
        #pragma unroll
        for (int j = 0; j < 16; j++) { s1 += hf[j]; s2 += hf[j] * hf[j]; }
        #pragma unroll
        for (int off = 32; off; off >>= 1) {
            s1 += __shfl_xor(s1, off);
            s2 += __shfl_xor(s2, off);
        }
        const float mu = s1 * (1.0f / 1024.0f);
        const float var = s2 * (1.0f / 1024.0f) - mu * mu;
        const float rstd = rsqrtf(var + 1e-5f) * m;       // mask by multiply (branch-free)
        #pragma unroll
        for (int j = 0; j < 16; j++) pacc[j] += (hf[j] - mu) * rstd * g16[j];
    }
    __shared__ float spool[4][1024];
    #pragma unroll
    for (int j = 0; j < 4; j++)
        *(float4*)&spool[wave][c0 + j * 4] = *(float4*)&pacc[j * 4];
    __syncthreads();
    const int ch = tid * 4;
    float4 a = *(float4*)&spool[0][ch];
    float4 bq = *(float4*)&spool[1][ch];
    float4 cq = *(float4*)&spool[2][ch];
    float4 dq = *(float4*)&spool[3][ch];
    atomicAdd(&pooled[b * Ww + ch + 0], a.x + bq.x + cq.x + dq.x);
    atomicAdd(&pooled[b * Ww + ch + 1], a.y + bq.y + cq.y + dq.y);
    atomicAdd(&pooled[b * Ww + ch + 2], a.z + bq.z + cq.z + dq.z);
    atomicAdd(&pooled[b * Ww + ch + 3], a.w + bq.w + cq.w + dq.w);
}

// ---------- kernel 4: lengths + projection (beta folded: + sum(beta*proj)) ----------
__global__ void final_kernel(const float* __restrict__ pooled, const float* __restrict__ maskf,
                             const float* __restrict__ beta, const float* __restrict__ proj_w,
                             const float* __restrict__ proj_b, float* __restrict__ out)
{
    int b = blockIdx.x;
    int tid = threadIdx.x;
    float len = 0.f, dotP = 0.f, dotB = 0.f;
    for (int l = tid; l < Ll; l += 256) len += maskf[b * Ll + l];
    for (int c = tid; c < Ww; c += 256) {
        dotP += pooled[b * Ww + c] * proj_w[c];
        dotB += beta[c] * proj_w[c];
    }
    for (int off = 32; off; off >>= 1) {
        len += __shfl_down(len, off);
        dotP += __shfl_down(dotP, off);
        dotB += __shfl_down(dotB, off);
    }
    __shared__ float rl[4], rp[4], rb[4];
    int wave = tid >> 6, lane = tid & 63;
    if (lane == 0) { rl[wave] = len; rp[wave] = dotP; rb[wave] = dotB; }
    __syncthreads();
    if (tid == 0) {
        float Lt = rl[0] + rl[1] + rl[2] + rl[3];
        float Pt = rp[0] + rp[1] + rp[2] + rp[3];
        float Bt = rb[0] + rb[1] + rb[2] + rb[3];
        out[b] = Pt / fmaxf(Lt, 1.0f) + Bt + proj_b[0];
    }
}

// ---------- workspace layout (bytes, 16B-aligned) ----------
// maskf  @        0  (65536)
// pooled @    65536  (32768)
// flags  @    98304  (16)
// pk     @    98320  (1310720)   [16384][5] float4
// w_t    @  1409040  (5242880)   640 images x 8KB
// x_bf   @  6651920  (33554432)  [16384][1024] bf16 plain
// h      @ 40206352  (33554432)  [16384][1024] bf16
// total 73,760,784 B

extern "C" void kernel_launch(void* const* d_in, const int* in_sizes, int n_in,
                              void* d_out, int out_size, void* d_ws, size_t ws_size,
                              hipStream_t stream)
{
    const float* x      = (const float*)d_in[0];
    const void*  mask   = d_in[1];
    const float* w_off  = (const float*)d_in[2];
    const float* b_off  = (const float*)d_in[3];
    const float* conv_w = (const float*)d_in[4];
    const float* conv_b = (const float*)d_in[5];
    const float* gamma  = (const float*)d_in[6];
    const float* beta   = (const float*)d_in[7];
    const float* proj_w = (const float*)d_in[8];
    const float* proj_b = (const float*)d_in[9];
    float* out = (float*)d_out;

    char* ws = (char*)d_ws;
    float* maskf         = (float*)(ws + 0);
    float* pooled        = (float*)(ws + 65536);
    int*   flags         = (int*)(ws + 98304);
    float4* pk           = (float4*)(ws + 98320);
    unsigned short* w_t  = (unsigned short*)(ws + 1409040);
    unsigned short* x_bf = (unsigned short*)(ws + 6651920);
    unsigned short* h    = (unsigned short*)(ws + 40206352);

    hipMemsetAsync(pooled, 0, Bb * Ww * sizeof(float), stream);
    hipMemsetAsync(flags, 0, 16, stream);
    maskA_kernel<<<16, 256, 0, stream>>>(mask, flags);
    maskB_kernel<<<16, 256, 0, stream>>>(mask, flags, maskf);
    wconv_kernel<<<160, 256, 0, stream>>>(conv_w, w_t);
    offsets_kernel<<<BL / 4, 256, 0, stream>>>(x, w_off, b_off, x_bf, pk);
    gemm_kernel<<<dim3(128, 2, 2), 256, 0, stream>>>(x_bf, w_t, pk, conv_b, h);
    lnpool_kernel<<<1024, 256, 0, stream>>>(h, gamma, maskf, pooled);
    final_kernel<<<8, 256, 0, stream>>>(pooled, maskf, beta, proj_w, proj_b, out);
}